// Round 2
// baseline (402.145 us; speedup 1.0000x reference)
//
#include <hip/hip_runtime.h>
#include <hip/hip_bf16.h>
#include <stdint.h>

#define HN 16
#define HH 224
#define HWD 224
#define HWP (HH*HWD)      // 50176
#define PH 112
#define PW 112
#define PHW (PH*PW)       // 12544
#define FCK 200704
#define KSEG 196

// ---------------- selector masks (depth-only, shared by both convs) ----------------
__global__ __launch_bounds__(256) void sel_kernel(
    const float* __restrict__ depth, const float* __restrict__ fxp,
    uint32_t* __restrict__ sel) {
  int idx = blockIdx.x*256 + threadIdx.x;           // 16*224*224 = 3136*256 exact
  int w = idx % HWD; int h = (idx / HWD) % HH; int n = idx / HWP;
  const float* dn = depth + n*HWP;
  float c = dn[h*HWD + w];
  float fx = fxp[0];
  float gr = c / fx;
  float half = gr * 0.5f;
  uint32_t bits = 0;
  #pragma unroll
  for (int i = 0; i < 3; ++i)
    #pragma unroll
    for (int j = 0; j < 3; ++j) {
      int y = h + i - 1, x = w + j - 1;
      float d = 0.0f;
      if (y >= 0 && y < HH && x >= 0 && x < HWD) d = dn[y*HWD + x];
      int k = i*3 + j;
      uint32_t b = 0;
      if (fabsf(d - (c + gr)) <= half) b |= 1u;   // m0 -> w0
      if (fabsf(d - c) < half)         b |= 2u;   // m1 -> w1 (strict <)
      if (fabsf(d - (c - gr)) <= half) b |= 4u;   // m2 -> w2
      bits |= b << (3*k);
    }
  sel[idx] = bits;
}

// ---------------- conv1: 3->16, thread per pixel ----------------
// weight LDS layout [kc][j][o]: per (k,c) gather = 4x ds_read_b128 (was 16x strided b32)
__global__ __launch_bounds__(256) void conv1_kernel(
    const float* __restrict__ x, const uint32_t* __restrict__ sel,
    const float* __restrict__ w0, const float* __restrict__ w1,
    const float* __restrict__ w2, const float* __restrict__ bias,
    float* __restrict__ h1t) {
  __shared__ __align__(16) float wl[1728];   // t = ((kc)*4 + j)*16 + o ; j==3 slot = zeros
  int tid = threadIdx.x;
  for (int t = tid; t < 1728; t += 256) {
    int o = t & 15; int j = (t >> 4) & 3; int kc = t >> 6;
    int c = kc % 3; int k = kc / 3;
    float v = 0.f;
    if (j == 0) v = w0[o*27 + c*9 + k];
    else if (j == 1) v = w1[o*27 + c*9 + k];
    else if (j == 2) v = w2[o*27 + c*9 + k];
    wl[t] = v;
  }
  __syncthreads();
  int idx = blockIdx.x*256 + tid;
  int w = idx % HWD; int h = (idx / HWD) % HH; int n = idx / HWP;
  uint32_t bits = sel[idx];
  const float* xn = x + n*3*HWP;
  float acc[16];
  #pragma unroll
  for (int o = 0; o < 16; ++o) acc[o] = 0.f;
  #pragma unroll
  for (int k = 0; k < 9; ++k) {
    uint32_t b = (bits >> (3*k)) & 7u;
    int jsel = (b & 1) ? 0 : (b & 2) ? 1 : (b & 4) ? 2 : 3;
    int y = h + k/3 - 1; int xx = w + (k%3) - 1;
    y = min(max(y,0), HH-1); xx = min(max(xx,0), HWD-1);   // clamped; OOB taps have bits==0
    const float* xp = xn + y*HWD + xx;
    #pragma unroll
    for (int c = 0; c < 3; ++c) {
      float xc = xp[c*HWP];
      const float4* wp = (const float4*)&wl[((k*3 + c)*4 + jsel)*16];
      float4 a = wp[0], b4 = wp[1], c4 = wp[2], d4 = wp[3];
      acc[0]  += a.x*xc;  acc[1]  += a.y*xc;  acc[2]  += a.z*xc;  acc[3]  += a.w*xc;
      acc[4]  += b4.x*xc; acc[5]  += b4.y*xc; acc[6]  += b4.z*xc; acc[7]  += b4.w*xc;
      acc[8]  += c4.x*xc; acc[9]  += c4.y*xc; acc[10] += c4.z*xc; acc[11] += c4.w*xc;
      acc[12] += d4.x*xc; acc[13] += d4.y*xc; acc[14] += d4.z*xc; acc[15] += d4.w*xc;
    }
  }
  float4 s[4];
  #pragma unroll
  for (int o = 0; o < 16; ++o)
    ((float*)s)[o] = fmaxf(acc[o] + bias[o], 0.f);
  float4* op = (float4*)(h1t + (size_t)idx*16);    // channel-last [n][h][w][16]
  op[0]=s[0]; op[1]=s[1]; op[2]=s[2]; op[3]=s[3];
}

// ---------------- conv2: 16->16 + ReLU + 2x2 maxpool ----------------
// wave per pooled-pixel-batch; lane=(cgrp,o); weights resident in VGPR (launch_bounds 256,1);
// x via 4x4 register window loaded UNCONDITIONALLY from global (L1-resident tile) --
// branches gate only register FMAs, no LDS broadcast reads.
__global__ __launch_bounds__(256, 1) void conv2_kernel(
    const float* __restrict__ h1t, const uint32_t* __restrict__ sel,
    const float* __restrict__ w0, const float* __restrict__ w1,
    const float* __restrict__ w2, const float* __restrict__ bias,
    float* __restrict__ outcf) {
  __shared__ float pl[64*17];                    // pooled tile [pix][o], padded
  int tid = threadIdx.x;
  int b = blockIdx.x;                            // 16n * 196 tiles
  int n = b / 196; int rem = b % 196;
  int br = rem / 14; int bc = rem % 14;
  int lane = tid & 63;
  int o = lane & 15, cgrp = lane >> 4;
  float4 wreg[3][9];                             // 108 floats/lane
  {
    const float* ws0[3] = {w0, w1, w2};
    #pragma unroll
    for (int j = 0; j < 3; ++j) {
      const float* wp = ws0[j] + o*144 + cgrp*36;
      #pragma unroll
      for (int k = 0; k < 9; ++k) {
        wreg[j][k].x = wp[0*9 + k];
        wreg[j][k].y = wp[1*9 + k];
        wreg[j][k].z = wp[2*9 + k];
        wreg[j][k].w = wp[3*9 + k];
      }
    }
  }
  float bo = bias[o];
  int wid = __builtin_amdgcn_readfirstlane(tid >> 6);
  const uint32_t* sn = sel + n*HWP;
  const float* hn = h1t + (size_t)n*HWP*16;
  for (int pp = 0; pp < 16; ++pp) {
    int pr = wid*2 + (pp >> 3);                  // pooled row in 8x8 tile
    int pc = pp & 7;                             // pooled col
    int gy0 = br*16 + pr*2 - 1;                  // window top-left (conv coords - 1)
    int gx0 = bc*16 + pc*2 - 1;
    float4 win[4][4];                            // 64 VGPR, unconditional loads
    #pragma unroll
    for (int r = 0; r < 4; ++r) {
      int ry = min(max(gy0 + r, 0), HH-1);
      #pragma unroll
      for (int c = 0; c < 4; ++c) {
        int rx = min(max(gx0 + c, 0), HWD-1);
        win[r][c] = *(const float4*)(hn + ((size_t)(ry*HWD + rx))*16 + cgrp*4);
      }
    }
    float pool = 0.f;                            // post-ReLU values are >= 0
    #pragma unroll
    for (int dy = 0; dy < 2; ++dy)
      #pragma unroll
      for (int dx = 0; dx < 2; ++dx) {
        uint32_t bits = sn[(gy0+1+dy)*HWD + (gx0+1+dx)];   // uniform -> s_load
        float acc = 0.f;
        #pragma unroll
        for (int k = 0; k < 9; ++k) {
          uint32_t bb = (bits >> (3*k)) & 7u;
          if (!bb) continue;                     // wave-uniform skip, regs already loaded
          const float4 xv = win[dy + k/3][dx + k%3];
          if (bb & 1u) acc += wreg[0][k].x*xv.x + wreg[0][k].y*xv.y + wreg[0][k].z*xv.z + wreg[0][k].w*xv.w;
          if (bb & 2u) acc += wreg[1][k].x*xv.x + wreg[1][k].y*xv.y + wreg[1][k].z*xv.z + wreg[1][k].w*xv.w;
          if (bb & 4u) acc += wreg[2][k].x*xv.x + wreg[2][k].y*xv.y + wreg[2][k].z*xv.z + wreg[2][k].w*xv.w;
        }
        acc += __shfl_xor(acc, 16, 64);          // reduce over 4 c-groups
        acc += __shfl_xor(acc, 32, 64);
        float v = fmaxf(acc + bo, 0.f);
        pool = fmaxf(pool, v);
      }
    if (lane < 16) pl[(pr*8 + pc)*17 + o] = pool;
  }
  __syncthreads();
  for (int t = tid; t < 1024; t += 256) {        // repack to channel-first for FC1
    int oo = t >> 6; int pix = t & 63;
    int r = pix >> 3, col = pix & 7;
    outcf[(size_t)((n*16 + oo)*PH + br*8 + r)*PW + bc*8 + col] = pl[pix*17 + oo];
  }
}

// ---------------- FC1: C[16,128] = h[16,K] * W^T, split-K with LDS tiles ----------------
__global__ __launch_bounds__(256) void fc1_kernel(
    const float* __restrict__ hin, const float* __restrict__ wgt,
    float* __restrict__ partial) {
  __shared__ __align__(16) float hl[16*132];
  __shared__ __align__(16) float wl[16*132];
  int tid = threadIdx.x;
  int otile = blockIdx.x & 7;      // 8 tiles of 16 outputs
  int kseg  = blockIdx.x >> 3;     // 196 segments
  int obase = otile << 4;
  int nn = tid >> 4, oo = tid & 15;
  float acc = 0.f;
  int kb = kseg * (8*128);
  for (int ch = 0; ch < 8; ++ch, kb += 128) {
    __syncthreads();
    int r = tid >> 7; int f = tid & 127;
    #pragma unroll
    for (int rr = 0; rr < 8; ++rr) {
      int row = (rr << 1) | r;
      hl[row*132 + f] = hin[row*FCK + kb + f];
      wl[row*132 + f] = wgt[(size_t)(obase + row)*FCK + kb + f];
    }
    __syncthreads();
    const float4* hp = (const float4*)&hl[nn*132];
    const float4* wp = (const float4*)&wl[oo*132];
    #pragma unroll
    for (int q = 0; q < 32; ++q) {
      float4 a = hp[q], bq = wp[q];
      acc += a.x*bq.x + a.y*bq.y + a.z*bq.z + a.w*bq.w;
    }
  }
  partial[(size_t)(kseg*16 + nn)*128 + obase + oo] = acc;
}

__global__ __launch_bounds__(256) void fc1_reduce_kernel(
    const float* __restrict__ partial, const float* __restrict__ bias,
    float* __restrict__ outp) {
  int idx = blockIdx.x*256 + threadIdx.x;   // 2048
  int o = idx & 127;
  float s = bias[o];
  for (int k = 0; k < KSEG; ++k) s += partial[(size_t)k*2048 + idx];
  outp[idx] = s;
}

// ---------------- FC2 + log_softmax ----------------
__global__ __launch_bounds__(128) void fc2_kernel(
    const float* __restrict__ fin, const float* __restrict__ w,
    const float* __restrict__ b, float* __restrict__ out) {
  __shared__ float row[128];
  __shared__ float v[10];
  __shared__ float lse;
  int n = blockIdx.x, t = threadIdx.x;
  row[t] = fin[n*128 + t];
  __syncthreads();
  if (t < 10) {
    float s = b[t];
    const float* wr = w + t*128;
    for (int i = 0; i < 128; ++i) s += row[i]*wr[i];
    v[t] = s;
  }
  __syncthreads();
  if (t == 0) {
    float m = v[0];
    for (int i = 1; i < 10; ++i) m = fmaxf(m, v[i]);
    float se = 0.f;
    for (int i = 0; i < 10; ++i) se += expf(v[i] - m);
    lse = m + logf(se);
  }
  __syncthreads();
  if (t < 10) out[n*10 + t] = v[t] - lse;
}

extern "C" void kernel_launch(void* const* d_in, const int* in_sizes, int n_in,
                              void* d_out, int out_size, void* d_ws, size_t ws_size,
                              hipStream_t stream) {
  const float* x     = (const float*)d_in[0];
  const float* depth = (const float*)d_in[1];
  const float* fx    = (const float*)d_in[2];
  const float* c1w0  = (const float*)d_in[3];
  const float* c1w1  = (const float*)d_in[4];
  const float* c1w2  = (const float*)d_in[5];
  const float* c1b   = (const float*)d_in[6];
  const float* c2w0  = (const float*)d_in[7];
  const float* c2w1  = (const float*)d_in[8];
  const float* c2w2  = (const float*)d_in[9];
  const float* c2b   = (const float*)d_in[10];
  const float* fc1w  = (const float*)d_in[11];
  const float* fc1b  = (const float*)d_in[12];
  const float* fc2w  = (const float*)d_in[13];
  const float* fc2b  = (const float*)d_in[14];
  float* out = (float*)d_out;

  char* ws = (char*)d_ws;
  uint32_t* sel  = (uint32_t*)ws;                                        // 3,211,264 B
  float* h1t     = (float*)(ws + 3211264);                               // 51,380,224 B
  float* pooled  = (float*)(ws + 3211264 + 51380224);                    // 12,845,056 B
  float* partial = (float*)(ws + 3211264 + 51380224 + 12845056);         // 1,605,632 B
  float* fc1o    = (float*)(ws + 3211264 + 51380224 + 12845056 + 1605632); // 8,192 B

  sel_kernel<<<3136, 256, 0, stream>>>(depth, fx, sel);
  conv1_kernel<<<3136, 256, 0, stream>>>(x, sel, c1w0, c1w1, c1w2, c1b, h1t);
  conv2_kernel<<<3136, 256, 0, stream>>>(h1t, sel, c2w0, c2w1, c2w2, c2b, pooled);
  fc1_kernel<<<1568, 256, 0, stream>>>(pooled, fc1w, partial);
  fc1_reduce_kernel<<<8, 256, 0, stream>>>(partial, fc1b, fc1o);
  fc2_kernel<<<16, 128, 0, stream>>>(fc1o, fc2w, fc2b, out);
}

// Round 3
// 280.673 us; speedup vs baseline: 1.4328x; 1.4328x over previous
//
#include <hip/hip_runtime.h>
#include <hip/hip_bf16.h>
#include <hip/hip_fp16.h>
#include <stdint.h>

#define HN 16
#define HH 224
#define HWD 224
#define HWP (HH*HWD)      // 50176
#define PH 112
#define PW 112
#define PHW (PH*PW)       // 12544
#define FCK 200704
#define KSEG 196

typedef _Float16 h2v __attribute__((ext_vector_type(2)));

static __device__ __forceinline__ float dot2h(uint32_t w, uint32_t x, float acc) {
#if __has_builtin(__builtin_amdgcn_fdot2)
  return __builtin_amdgcn_fdot2(__builtin_bit_cast(h2v, w), __builtin_bit_cast(h2v, x), acc, false);
#else
  h2v wv = __builtin_bit_cast(h2v, w), xv = __builtin_bit_cast(h2v, x);
  return acc + (float)wv.x*(float)xv.x + (float)wv.y*(float)xv.y;
#endif
}

// ---------------- selector masks (depth-only, shared by both convs) ----------------
__global__ __launch_bounds__(256) void sel_kernel(
    const float* __restrict__ depth, const float* __restrict__ fxp,
    uint32_t* __restrict__ sel) {
  int idx = blockIdx.x*256 + threadIdx.x;           // 16*224*224 = 3136*256 exact
  int w = idx % HWD; int h = (idx / HWD) % HH; int n = idx / HWP;
  const float* dn = depth + n*HWP;
  float c = dn[h*HWD + w];
  float fx = fxp[0];
  float gr = c / fx;
  float half = gr * 0.5f;
  uint32_t bits = 0;
  #pragma unroll
  for (int i = 0; i < 3; ++i)
    #pragma unroll
    for (int j = 0; j < 3; ++j) {
      int y = h + i - 1, x = w + j - 1;
      float d = 0.0f;
      if (y >= 0 && y < HH && x >= 0 && x < HWD) d = dn[y*HWD + x];
      int k = i*3 + j;
      uint32_t b = 0;
      if (fabsf(d - (c + gr)) <= half) b |= 1u;   // m0 -> w0
      if (fabsf(d - c) < half)         b |= 2u;   // m1 -> w1 (strict <)
      if (fabsf(d - (c - gr)) <= half) b |= 4u;   // m2 -> w2
      bits |= b << (3*k);
    }
  sel[idx] = bits;
}

// ---------------- conv1: 3->16, thread per pixel, f16 channel-last output ----------------
__global__ __launch_bounds__(256) void conv1_kernel(
    const float* __restrict__ x, const uint32_t* __restrict__ sel,
    const float* __restrict__ w0, const float* __restrict__ w1,
    const float* __restrict__ w2, const float* __restrict__ bias,
    __half* __restrict__ h1t) {
  __shared__ __align__(16) float wl[1728];   // t = ((kc)*4 + j)*16 + o ; j==3 slot = zeros
  int tid = threadIdx.x;
  for (int t = tid; t < 1728; t += 256) {
    int o = t & 15; int j = (t >> 4) & 3; int kc = t >> 6;
    int c = kc % 3; int k = kc / 3;
    float v = 0.f;
    if (j == 0) v = w0[o*27 + c*9 + k];
    else if (j == 1) v = w1[o*27 + c*9 + k];
    else if (j == 2) v = w2[o*27 + c*9 + k];
    wl[t] = v;
  }
  __syncthreads();
  int idx = blockIdx.x*256 + tid;
  int w = idx % HWD; int h = (idx / HWD) % HH; int n = idx / HWP;
  uint32_t bits = sel[idx];
  const float* xn = x + n*3*HWP;
  float acc[16];
  #pragma unroll
  for (int o = 0; o < 16; ++o) acc[o] = 0.f;
  #pragma unroll
  for (int k = 0; k < 9; ++k) {
    uint32_t b = (bits >> (3*k)) & 7u;
    int jsel = (b & 1) ? 0 : (b & 2) ? 1 : (b & 4) ? 2 : 3;
    int y = h + k/3 - 1; int xx = w + (k%3) - 1;
    y = min(max(y,0), HH-1); xx = min(max(xx,0), HWD-1);   // clamped; OOB taps have bits==0
    const float* xp = xn + y*HWD + xx;
    #pragma unroll
    for (int c = 0; c < 3; ++c) {
      float xc = xp[c*HWP];
      const float4* wp = (const float4*)&wl[((k*3 + c)*4 + jsel)*16];
      float4 a = wp[0], b4 = wp[1], c4 = wp[2], d4 = wp[3];
      acc[0]  += a.x*xc;  acc[1]  += a.y*xc;  acc[2]  += a.z*xc;  acc[3]  += a.w*xc;
      acc[4]  += b4.x*xc; acc[5]  += b4.y*xc; acc[6]  += b4.z*xc; acc[7]  += b4.w*xc;
      acc[8]  += c4.x*xc; acc[9]  += c4.y*xc; acc[10] += c4.z*xc; acc[11] += c4.w*xc;
      acc[12] += d4.x*xc; acc[13] += d4.y*xc; acc[14] += d4.z*xc; acc[15] += d4.w*xc;
    }
  }
  __half hs[16];
  #pragma unroll
  for (int o = 0; o < 16; ++o)
    hs[o] = __float2half(fmaxf(acc[o] + bias[o], 0.f));
  uint4* op = (uint4*)(h1t + (size_t)idx*16);    // channel-last [n][h][w][16], 32B/px
  op[0] = ((uint4*)hs)[0];
  op[1] = ((uint4*)hs)[1];
}

// ---------------- conv2: 16->16 + ReLU + 2x2 maxpool ----------------
// f16 x (LDS tile) and f16 weights (54 VGPR as half2 pairs), v_dot2_f32_f16 inner product.
// wave per pooled px; lane=(cgrp,o); 4x4 window = 32 VGPR, unconditional LDS b64 loads;
// wave-uniform selector branches gate only register dot2s.
__global__ __launch_bounds__(256, 3) void conv2_kernel(
    const __half* __restrict__ h1t, const uint32_t* __restrict__ sel,
    const float* __restrict__ w0, const float* __restrict__ w1,
    const float* __restrict__ w2, const float* __restrict__ bias,
    float* __restrict__ outcf) {
  __shared__ __align__(16) __half ts[18*18*16];  // 10368 B staged tile [y][x][c]
  __shared__ float pl[64*17];                    // pooled tile [pix][o], padded
  int tid = threadIdx.x;
  int b = blockIdx.x;                            // 16n * 196 tiles
  int n = b / 196; int rem = b % 196;
  int br = rem / 14; int bc = rem % 14;
  int y0 = br*16 - 1;
  int x0 = bc*16 - 1;
  const __half* hn = h1t + (size_t)n*HWP*16;
  // stage tile as u32 (c-pairs): 2592 words
  for (int t = tid; t < 2592; t += 256) {
    int cp = t & 7; int p = t >> 3;
    int gy = min(max(y0 + p/18, 0), HH-1);
    int gx = min(max(x0 + p%18, 0), HWD-1);
    ((uint32_t*)ts)[t] = *(const uint32_t*)(hn + ((size_t)(gy*HWD + gx))*16 + cp*2);
  }
  int lane = tid & 63;
  int o = lane & 15, cgrp = lane >> 4;
  uint32_t wh[3][9][2];                          // 54 VGPR: half2 (c0,c1),(c2,c3)
  {
    const float* ws0[3] = {w0, w1, w2};
    #pragma unroll
    for (int j = 0; j < 3; ++j) {
      const float* wp = ws0[j] + o*144 + cgrp*36;
      #pragma unroll
      for (int k = 0; k < 9; ++k) {
        __half2 lo = __floats2half2_rn(wp[0*9 + k], wp[1*9 + k]);
        __half2 hi = __floats2half2_rn(wp[2*9 + k], wp[3*9 + k]);
        wh[j][k][0] = __builtin_bit_cast(uint32_t, lo);
        wh[j][k][1] = __builtin_bit_cast(uint32_t, hi);
      }
    }
  }
  float bo = bias[o];
  __syncthreads();
  int wid = __builtin_amdgcn_readfirstlane(tid >> 6);
  const uint32_t* sn = sel + n*HWP;
  for (int pp = 0; pp < 16; ++pp) {
    int pr = wid*2 + (pp >> 3);                  // pooled row in 8x8 tile
    int pc = pp & 7;                             // pooled col
    int ty0 = pr*2, tx0 = pc*2;                  // window top-left in tile coords
    uint2 win[4][4];                             // 32 VGPR, unconditional b64 loads
    #pragma unroll
    for (int r = 0; r < 4; ++r)
      #pragma unroll
      for (int c = 0; c < 4; ++c)
        win[r][c] = *(const uint2*)(ts + ((ty0 + r)*18 + (tx0 + c))*16 + cgrp*4);
    float pool = 0.f;                            // post-ReLU values are >= 0
    #pragma unroll
    for (int dy = 0; dy < 2; ++dy)
      #pragma unroll
      for (int dx = 0; dx < 2; ++dx) {
        int gy = br*16 + pr*2 + dy, gx = bc*16 + pc*2 + dx;
        uint32_t bits = sn[gy*HWD + gx];         // wave-uniform
        float acc = 0.f;
        #pragma unroll
        for (int k = 0; k < 9; ++k) {
          uint32_t bb = (bits >> (3*k)) & 7u;
          if (!bb) continue;                     // wave-uniform skip
          const uint2 xv = win[dy + k/3][dx + k%3];
          if (bb & 1u)      { acc = dot2h(wh[0][k][0], xv.x, acc); acc = dot2h(wh[0][k][1], xv.y, acc); }
          else if (bb & 2u) { acc = dot2h(wh[1][k][0], xv.x, acc); acc = dot2h(wh[1][k][1], xv.y, acc); }
          else              { acc = dot2h(wh[2][k][0], xv.x, acc); acc = dot2h(wh[2][k][1], xv.y, acc); }
        }
        acc += __shfl_xor(acc, 16, 64);          // reduce over 4 c-groups
        acc += __shfl_xor(acc, 32, 64);
        float v = fmaxf(acc + bo, 0.f);
        pool = fmaxf(pool, v);
      }
    if (lane < 16) pl[(pr*8 + pc)*17 + o] = pool;
  }
  __syncthreads();
  for (int t = tid; t < 1024; t += 256) {        // repack to channel-first for FC1
    int oo = t >> 6; int pix = t & 63;
    int r = pix >> 3, col = pix & 7;
    outcf[(size_t)((n*16 + oo)*PH + br*8 + r)*PW + bc*8 + col] = pl[pix*17 + oo];
  }
}

// ---------------- FC1: C[16,128] = h[16,K] * W^T, split-K with LDS tiles ----------------
__global__ __launch_bounds__(256) void fc1_kernel(
    const float* __restrict__ hin, const float* __restrict__ wgt,
    float* __restrict__ partial) {
  __shared__ __align__(16) float hl[16*132];
  __shared__ __align__(16) float wl[16*132];
  int tid = threadIdx.x;
  int otile = blockIdx.x & 7;      // 8 tiles of 16 outputs
  int kseg  = blockIdx.x >> 3;     // 196 segments
  int obase = otile << 4;
  int nn = tid >> 4, oo = tid & 15;
  float acc = 0.f;
  int kb = kseg * (8*128);
  for (int ch = 0; ch < 8; ++ch, kb += 128) {
    __syncthreads();
    int r = tid >> 7; int f = tid & 127;
    #pragma unroll
    for (int rr = 0; rr < 8; ++rr) {
      int row = (rr << 1) | r;
      hl[row*132 + f] = hin[row*FCK + kb + f];
      wl[row*132 + f] = wgt[(size_t)(obase + row)*FCK + kb + f];
    }
    __syncthreads();
    const float4* hp = (const float4*)&hl[nn*132];
    const float4* wp = (const float4*)&wl[oo*132];
    #pragma unroll
    for (int q = 0; q < 32; ++q) {
      float4 a = hp[q], bq = wp[q];
      acc += a.x*bq.x + a.y*bq.y + a.z*bq.z + a.w*bq.w;
    }
  }
  partial[(size_t)(kseg*16 + nn)*128 + obase + oo] = acc;
}

__global__ __launch_bounds__(256) void fc1_reduce_kernel(
    const float* __restrict__ partial, const float* __restrict__ bias,
    float* __restrict__ outp) {
  int idx = blockIdx.x*256 + threadIdx.x;   // 2048
  int o = idx & 127;
  float s = bias[o];
  for (int k = 0; k < KSEG; ++k) s += partial[(size_t)k*2048 + idx];
  outp[idx] = s;
}

// ---------------- FC2 + log_softmax ----------------
__global__ __launch_bounds__(128) void fc2_kernel(
    const float* __restrict__ fin, const float* __restrict__ w,
    const float* __restrict__ b, float* __restrict__ out) {
  __shared__ float row[128];
  __shared__ float v[10];
  __shared__ float lse;
  int n = blockIdx.x, t = threadIdx.x;
  row[t] = fin[n*128 + t];
  __syncthreads();
  if (t < 10) {
    float s = b[t];
    const float* wr = w + t*128;
    for (int i = 0; i < 128; ++i) s += row[i]*wr[i];
    v[t] = s;
  }
  __syncthreads();
  if (t == 0) {
    float m = v[0];
    for (int i = 1; i < 10; ++i) m = fmaxf(m, v[i]);
    float se = 0.f;
    for (int i = 0; i < 10; ++i) se += expf(v[i] - m);
    lse = m + logf(se);
  }
  __syncthreads();
  if (t < 10) out[n*10 + t] = v[t] - lse;
}

extern "C" void kernel_launch(void* const* d_in, const int* in_sizes, int n_in,
                              void* d_out, int out_size, void* d_ws, size_t ws_size,
                              hipStream_t stream) {
  const float* x     = (const float*)d_in[0];
  const float* depth = (const float*)d_in[1];
  const float* fx    = (const float*)d_in[2];
  const float* c1w0  = (const float*)d_in[3];
  const float* c1w1  = (const float*)d_in[4];
  const float* c1w2  = (const float*)d_in[5];
  const float* c1b   = (const float*)d_in[6];
  const float* c2w0  = (const float*)d_in[7];
  const float* c2w1  = (const float*)d_in[8];
  const float* c2w2  = (const float*)d_in[9];
  const float* c2b   = (const float*)d_in[10];
  const float* fc1w  = (const float*)d_in[11];
  const float* fc1b  = (const float*)d_in[12];
  const float* fc2w  = (const float*)d_in[13];
  const float* fc2b  = (const float*)d_in[14];
  float* out = (float*)d_out;

  char* ws = (char*)d_ws;
  uint32_t* sel  = (uint32_t*)ws;                                 // 3,211,264 B
  __half* h1t    = (__half*)(ws + 3211264);                       // 25,690,112 B (f16)
  float* pooled  = (float*)(ws + 28901376);                       // 12,845,056 B
  float* partial = (float*)(ws + 41746432);                       // 1,605,632 B
  float* fc1o    = (float*)(ws + 43352064);                       // 8,192 B

  sel_kernel<<<3136, 256, 0, stream>>>(depth, fx, sel);
  conv1_kernel<<<3136, 256, 0, stream>>>(x, sel, c1w0, c1w1, c1w2, c1b, h1t);
  conv2_kernel<<<3136, 256, 0, stream>>>(h1t, sel, c2w0, c2w1, c2w2, c2b, pooled);
  fc1_kernel<<<1568, 256, 0, stream>>>(pooled, fc1w, partial);
  fc1_reduce_kernel<<<8, 256, 0, stream>>>(partial, fc1b, fc1o);
  fc2_kernel<<<16, 128, 0, stream>>>(fc1o, fc2w, fc2b, out);
}

// Round 4
// 131.788 us; speedup vs baseline: 3.0515x; 2.1297x over previous
//
#include <hip/hip_runtime.h>
#include <hip/hip_fp16.h>
#include <stdint.h>

#define HH 224
#define HWD 224
#define HWP (HH*HWD)      // 50176
#define PH 112
#define PW 112
#define PHW (PH*PW)       // 12544
#define FCK 200704
#define KSEG 196

typedef _Float16 f16x8 __attribute__((ext_vector_type(8)));
typedef float f32x4 __attribute__((ext_vector_type(4)));

static __device__ __forceinline__ uint32_t pkh2(float a, float b) {
  __half2 h = __floats2half2_rn(a, b);
  return __builtin_bit_cast(uint32_t, h);
}
static __device__ __forceinline__ f32x4 mfma16(uint4 a, uint4 b, f32x4 c) {
  return __builtin_amdgcn_mfma_f32_16x16x32_f16(
      __builtin_bit_cast(f16x8, a), __builtin_bit_cast(f16x8, b), c, 0, 0, 0);
}

// ---------------- selector masks (depth-only, shared by both convs) ----------------
__global__ __launch_bounds__(256) void sel_kernel(
    const float* __restrict__ depth, const float* __restrict__ fxp,
    uint32_t* __restrict__ sel) {
  int idx = blockIdx.x*256 + threadIdx.x;           // 16*224*224 = 3136*256 exact
  int w = idx % HWD; int h = (idx / HWD) % HH; int n = idx / HWP;
  const float* dn = depth + n*HWP;
  float c = dn[h*HWD + w];
  float fx = fxp[0];
  float gr = c / fx;
  float half = gr * 0.5f;
  uint32_t bits = 0;
  #pragma unroll
  for (int i = 0; i < 3; ++i)
    #pragma unroll
    for (int j = 0; j < 3; ++j) {
      int y = h + i - 1, x = w + j - 1;
      float d = 0.0f;
      if (y >= 0 && y < HH && x >= 0 && x < HWD) d = dn[y*HWD + x];
      int k = i*3 + j;
      uint32_t b = 0;
      if (fabsf(d - (c + gr)) <= half) b |= 1u;   // m0 -> w0
      if (fabsf(d - c) < half)         b |= 2u;   // m1 -> w1 (strict <)
      if (fabsf(d - (c - gr)) <= half) b |= 4u;   // m2 -> w2
      bits |= b << (3*k);
    }
  sel[idx] = bits;
}

// ======== MFMA conv template notes ========
// A (M=16 px along x, K=32 = 2 taps x 16 c): lane l -> px row r=l&15,
//   k=(l>>4)*8+e; tap = l>>5 of the pair, c = ((l>>4)&1)*8+e.
// B: lane l -> o col = l&15, same k mapping; staged in frag order in LDS.
// C/D: lane l -> o = l&15, px = (l>>4)*4 + reg.
// Mask m_j[px, tap] is per-lane uniform across its 8 A elems -> AND-mask.

// ---------------- conv1: 3->16 via MFMA (c padded 3->16 with zeros) ----------------
__global__ __launch_bounds__(256, 2) void conv1_kernel(
    const float* __restrict__ x, const uint32_t* __restrict__ sel,
    const float* __restrict__ w0, const float* __restrict__ w1,
    const float* __restrict__ w2, const float* __restrict__ bias,
    __half* __restrict__ h1t) {
  __shared__ __align__(16) __half ts[18*18*24];   // x tile f16, [py][px][c pad 24]
  __shared__ __align__(16) uint4 wlds[15*64];     // B-frags, 15360 B
  __shared__ __half hbuf[4][256];                 // per-wave output bounce
  int tid = threadIdx.x;
  int b = blockIdx.x;
  int n = b / 196; int rem = b % 196;
  int br = rem / 14, bc = rem % 14;
  int y0 = br*16 - 1, x0 = bc*16 - 1;
  // zero ts (c 3..23 stay zero)
  for (int t = tid; t < 3888; t += 256) ((uint32_t*)ts)[t] = 0;
  __syncthreads();
  // fill c=0..2 from x (fp32 channel-first)
  const float* xn = x + (size_t)n*3*HWP;
  for (int t = tid; t < 972; t += 256) {
    int p = t % 324; int c = t / 324;
    int gy = min(max(y0 + p/18, 0), HH-1);
    int gx = min(max(x0 + p%18, 0), HWD-1);
    ts[(p/18*18 + p%18)*24 + c] = __float2half(xn[c*HWP + gy*HWD + gx]);
  }
  // stage B-frags (c>=3 zero, tap9 zero)
  for (int t = tid; t < 960; t += 256) {
    int lane = t & 63; int pj = t >> 6;
    int p = pj / 3, j = pj % 3;
    int o = lane & 15; int tap = p*2 + (lane >> 5);
    int cbase = ((lane >> 4) & 1) * 8;
    const float* wj = (j == 0) ? w0 : (j == 1) ? w1 : w2;
    float f[8];
    #pragma unroll
    for (int e = 0; e < 8; ++e) {
      int c = cbase + e;
      f[e] = (tap <= 8 && c < 3) ? wj[o*27 + c*9 + tap] : 0.f;
    }
    uint4 wv = { pkh2(f[0],f[1]), pkh2(f[2],f[3]), pkh2(f[4],f[5]), pkh2(f[6],f[7]) };
    wlds[pj*64 + lane] = wv;
  }
  int lane = tid & 63, wid = tid >> 6;
  int r = lane & 15;
  float bo = bias[r];
  uint32_t sv[4];
  #pragma unroll
  for (int ty = 0; ty < 4; ++ty)
    sv[ty] = sel[(size_t)n*HWP + (br*16 + wid*4 + ty)*HWD + bc*16 + r];
  int tapPar = lane >> 5;                  // 0 = even tap, 1 = odd tap of pair
  int c0 = ((lane >> 4) & 1) * 8;
  __syncthreads();
  f32x4 acc[4] = {{0,0,0,0},{0,0,0,0},{0,0,0,0},{0,0,0,0}};
  #pragma unroll
  for (int p = 0; p < 5; ++p) {
    int ta = 2*p, tb = (2*p+1 > 8) ? 8 : 2*p+1;     // tap9 dups tap8 (B=0 kills it)
    int dyL = tapPar ? tb/3 : ta/3;
    int dxL = tapPar ? tb%3 : ta%3;
    int shL = 3*(tapPar ? 2*p+1 : 2*p);             // tap9 shift=27 -> bits are 0
    uint4 a[4];
    #pragma unroll
    for (int ty = 0; ty < 4; ++ty) {
      int ly = wid*4 + ty;
      a[ty] = *(const uint4*)(ts + ((ly + dyL)*18 + (r + dxL))*24 + c0);
    }
    #pragma unroll
    for (int j = 0; j < 3; ++j) {
      uint4 bf = wlds[(p*3 + j)*64 + lane];
      #pragma unroll
      for (int ty = 0; ty < 4; ++ty) {
        uint32_t msk = 0u - ((sv[ty] >> (shL + j)) & 1u);
        uint4 am = { a[ty].x & msk, a[ty].y & msk, a[ty].z & msk, a[ty].w & msk };
        acc[ty] = mfma16(am, bf, acc[ty]);
      }
    }
  }
  // relu + write channel-last f16 (bounce via LDS for coalesced stores)
  #pragma unroll
  for (int ty = 0; ty < 4; ++ty) {
    int gy = br*16 + wid*4 + ty;
    #pragma unroll
    for (int e = 0; e < 4; ++e) {
      float v = fmaxf(acc[ty][e] + bo, 0.f);
      hbuf[wid][((lane>>4)*4 + e)*16 + r] = __float2half(v);
    }
    uint2 hw = *(uint2*)&hbuf[wid][lane*4];
    *(uint2*)(h1t + ((size_t)(n*HWP + gy*HWD) + bc*16)*16 + lane*4) = hw;
  }
}

// ---------------- conv2: 16->16 via MFMA + ReLU + 2x2 maxpool -> pooled f16 CF ----------------
__global__ __launch_bounds__(256, 2) void conv2_kernel(
    const __half* __restrict__ h1t, const uint32_t* __restrict__ sel,
    const float* __restrict__ w0, const float* __restrict__ w1,
    const float* __restrict__ w2, const float* __restrict__ bias,
    __half* __restrict__ pooled) {
  __shared__ __align__(16) __half ts[18*18*24];   // h1 tile f16, [py][px][c pad 24]
  __shared__ __align__(16) uint4 wlds[15*64];
  __shared__ float pl[64*17];
  int tid = threadIdx.x;
  int b = blockIdx.x;
  int n = b / 196; int rem = b % 196;
  int br = rem / 14, bc = rem % 14;
  int y0 = br*16 - 1, x0 = bc*16 - 1;
  const __half* hn = h1t + (size_t)n*HWP*16;
  for (int t = tid; t < 2592; t += 256) {         // stage tile (u32 = 2 c)
    int cp = t & 7; int p = t >> 3;
    int gy = min(max(y0 + p/18, 0), HH-1);
    int gx = min(max(x0 + p%18, 0), HWD-1);
    uint32_t v = *(const uint32_t*)(hn + ((size_t)(gy*HWD + gx))*16 + cp*2);
    *(uint32_t*)(ts + (p/18*18 + p%18)*24 + cp*2) = v;
  }
  for (int t = tid; t < 960; t += 256) {          // stage B-frags
    int lane = t & 63; int pj = t >> 6;
    int p = pj / 3, j = pj % 3;
    int o = lane & 15; int tap = p*2 + (lane >> 5);
    int cbase = ((lane >> 4) & 1) * 8;
    const float* wj = (j == 0) ? w0 : (j == 1) ? w1 : w2;
    uint4 wv;
    if (tap > 8) { wv.x = wv.y = wv.z = wv.w = 0; }
    else {
      const float* wp = wj + o*144 + cbase*9 + tap;   // [o][c][k]
      float f[8];
      #pragma unroll
      for (int e = 0; e < 8; ++e) f[e] = wp[e*9];
      wv.x = pkh2(f[0],f[1]); wv.y = pkh2(f[2],f[3]);
      wv.z = pkh2(f[4],f[5]); wv.w = pkh2(f[6],f[7]);
    }
    wlds[pj*64 + lane] = wv;
  }
  int lane = tid & 63, wid = tid >> 6;
  int r = lane & 15;
  float bo = bias[r];
  uint32_t sv[4];
  #pragma unroll
  for (int ty = 0; ty < 4; ++ty)
    sv[ty] = sel[(size_t)n*HWP + (br*16 + wid*4 + ty)*HWD + bc*16 + r];
  int tapPar = lane >> 5;
  int c0 = ((lane >> 4) & 1) * 8;
  __syncthreads();
  f32x4 acc[4] = {{0,0,0,0},{0,0,0,0},{0,0,0,0},{0,0,0,0}};
  #pragma unroll
  for (int p = 0; p < 5; ++p) {
    int ta = 2*p, tb = (2*p+1 > 8) ? 8 : 2*p+1;
    int dyL = tapPar ? tb/3 : ta/3;
    int dxL = tapPar ? tb%3 : ta%3;
    int shL = 3*(tapPar ? 2*p+1 : 2*p);
    uint4 a[4];
    #pragma unroll
    for (int ty = 0; ty < 4; ++ty) {
      int ly = wid*4 + ty;
      a[ty] = *(const uint4*)(ts + ((ly + dyL)*18 + (r + dxL))*24 + c0);
    }
    #pragma unroll
    for (int j = 0; j < 3; ++j) {
      uint4 bf = wlds[(p*3 + j)*64 + lane];
      #pragma unroll
      for (int ty = 0; ty < 4; ++ty) {
        uint32_t msk = 0u - ((sv[ty] >> (shL + j)) & 1u);
        uint4 am = { a[ty].x & msk, a[ty].y & msk, a[ty].z & msk, a[ty].w & msk };
        acc[ty] = mfma16(am, bf, acc[ty]);
      }
    }
  }
  // relu + 2x2 maxpool: x-pairs within lane regs, y-pairs across tiles
  #pragma unroll
  for (int yp = 0; yp < 2; ++yp) {
    f32x4 v0 = acc[yp*2], v1 = acc[yp*2+1];
    float m00 = fmaxf(fmaxf(v0[0]+bo, 0.f), fmaxf(v0[1]+bo, 0.f));
    float m01 = fmaxf(fmaxf(v0[2]+bo, 0.f), fmaxf(v0[3]+bo, 0.f));
    float m10 = fmaxf(fmaxf(v1[0]+bo, 0.f), fmaxf(v1[1]+bo, 0.f));
    float m11 = fmaxf(fmaxf(v1[2]+bo, 0.f), fmaxf(v1[3]+bo, 0.f));
    int prow = wid*2 + yp;
    int pc0 = (lane >> 4)*2;
    pl[(prow*8 + pc0)*17 + r]     = fmaxf(m00, m10);
    pl[(prow*8 + pc0 + 1)*17 + r] = fmaxf(m01, m11);
  }
  __syncthreads();
  for (int t = tid; t < 1024; t += 256) {         // repack channel-first f16
    int oo = t >> 6; int pix = t & 63;
    int pr = pix >> 3, pc = pix & 7;
    pooled[(size_t)(n*16 + oo)*PHW + (br*8 + pr)*PW + bc*8 + pc] =
        __float2half(pl[pix*17 + oo]);
  }
}

// ---------------- FC1 via MFMA: A=pooled f16 [16 x K], B=wgt f32->f16 ----------------
// block = (otile 0..7)*196 + kseg; K-slice 1024 = 8 chunks x 128; wave w owns kstep w.
__global__ __launch_bounds__(256) void fc1_kernel(
    const __half* __restrict__ hin, const float* __restrict__ wgt,
    float* __restrict__ partial) {
  __shared__ __align__(16) uint4 alds[4*64];
  __shared__ __align__(16) uint4 wlds[4*64];
  __shared__ __align__(16) f32x4 cacc[256];
  int tid = threadIdx.x;
  int otile = blockIdx.x / 196;
  int kseg  = blockIdx.x % 196;
  int obase = otile * 16;
  int lane = tid & 63, wid = tid >> 6;
  int q8 = tid & 15, row = tid >> 4;              // staging coords (16 rows x 16 k-octs)
  f32x4 acc = {0,0,0,0};
  for (int ch = 0; ch < 8; ++ch) {
    int kb = kseg*1024 + ch*128;
    __syncthreads();
    { // stage A: 16 n x 128 k f16
      uint4 hv = *(const uint4*)(hin + (size_t)row*FCK + kb + q8*8);
      alds[(q8>>2)*64 + (row | ((q8&3) << 4))] = hv;
    }
    { // stage B: 16 o x 128 k f32 -> f16
      const float* wp = wgt + (size_t)(obase + row)*FCK + kb + q8*8;
      float4 wa = *(const float4*)wp;
      float4 wb = *(const float4*)(wp + 4);
      uint4 wc = { pkh2(wa.x,wa.y), pkh2(wa.z,wa.w), pkh2(wb.x,wb.y), pkh2(wb.z,wb.w) };
      wlds[(q8>>2)*64 + (row | ((q8&3) << 4))] = wc;
    }
    __syncthreads();
    acc = mfma16(alds[wid*64 + lane], wlds[wid*64 + lane], acc);
  }
  cacc[wid*64 + lane] = acc;
  __syncthreads();
  {
    int l = tid & 63, e = tid >> 6;
    float s = cacc[l][e] + cacc[64 + l][e] + cacc[128 + l][e] + cacc[192 + l][e];
    int nn = (l >> 4)*4 + e;
    int oo = l & 15;
    partial[((size_t)kseg*16 + nn)*128 + obase + oo] = s;
  }
}

__global__ __launch_bounds__(256) void fc1_reduce_kernel(
    const float* __restrict__ partial, const float* __restrict__ bias,
    float* __restrict__ outp) {
  int idx = blockIdx.x*256 + threadIdx.x;   // 2048
  int o = idx & 127;
  float s = bias[o];
  for (int k = 0; k < KSEG; ++k) s += partial[(size_t)k*2048 + idx];
  outp[idx] = s;
}

// ---------------- FC2 + log_softmax ----------------
__global__ __launch_bounds__(128) void fc2_kernel(
    const float* __restrict__ fin, const float* __restrict__ w,
    const float* __restrict__ b, float* __restrict__ out) {
  __shared__ float row[128];
  __shared__ float v[10];
  __shared__ float lse;
  int n = blockIdx.x, t = threadIdx.x;
  row[t] = fin[n*128 + t];
  __syncthreads();
  if (t < 10) {
    float s = b[t];
    const float* wr = w + t*128;
    for (int i = 0; i < 128; ++i) s += row[i]*wr[i];
    v[t] = s;
  }
  __syncthreads();
  if (t == 0) {
    float m = v[0];
    for (int i = 1; i < 10; ++i) m = fmaxf(m, v[i]);
    float se = 0.f;
    for (int i = 0; i < 10; ++i) se += expf(v[i] - m);
    lse = m + logf(se);
  }
  __syncthreads();
  if (t < 10) out[n*10 + t] = v[t] - lse;
}

extern "C" void kernel_launch(void* const* d_in, const int* in_sizes, int n_in,
                              void* d_out, int out_size, void* d_ws, size_t ws_size,
                              hipStream_t stream) {
  const float* x     = (const float*)d_in[0];
  const float* depth = (const float*)d_in[1];
  const float* fx    = (const float*)d_in[2];
  const float* c1w0  = (const float*)d_in[3];
  const float* c1w1  = (const float*)d_in[4];
  const float* c1w2  = (const float*)d_in[5];
  const float* c1b   = (const float*)d_in[6];
  const float* c2w0  = (const float*)d_in[7];
  const float* c2w1  = (const float*)d_in[8];
  const float* c2w2  = (const float*)d_in[9];
  const float* c2b   = (const float*)d_in[10];
  const float* fc1w  = (const float*)d_in[11];
  const float* fc1b  = (const float*)d_in[12];
  const float* fc2w  = (const float*)d_in[13];
  const float* fc2b  = (const float*)d_in[14];
  float* out = (float*)d_out;

  char* ws = (char*)d_ws;
  uint32_t* sel  = (uint32_t*)ws;                      // 3,211,264 B
  __half* h1t    = (__half*)(ws + 3211264);            // 25,690,112 B
  __half* pooled = (__half*)(ws + 28901376);           //  6,422,528 B
  float* partial = (float*)(ws + 35323904);            //  1,605,632 B
  float* fc1o    = (float*)(ws + 36929536);            //      8,192 B

  sel_kernel<<<3136, 256, 0, stream>>>(depth, fx, sel);
  conv1_kernel<<<3136, 256, 0, stream>>>(x, sel, c1w0, c1w1, c1w2, c1b, h1t);
  conv2_kernel<<<3136, 256, 0, stream>>>(h1t, sel, c2w0, c2w1, c2w2, c2b, pooled);
  fc1_kernel<<<1568, 256, 0, stream>>>(pooled, fc1w, partial);
  fc1_reduce_kernel<<<8, 256, 0, stream>>>(partial, fc1b, fc1o);
  fc2_kernel<<<16, 128, 0, stream>>>(fc1o, fc2w, fc2b, out);
}

// Round 5
// 123.228 us; speedup vs baseline: 3.2634x; 1.0695x over previous
//
#include <hip/hip_runtime.h>
#include <hip/hip_fp16.h>
#include <stdint.h>

#define HH 224
#define HWD 224
#define HWP (HH*HWD)      // 50176
#define PH 112
#define PW 112
#define PHW (PH*PW)       // 12544
#define FCK 200704
#define KSEG 196

typedef _Float16 f16x8 __attribute__((ext_vector_type(8)));
typedef float f32x4 __attribute__((ext_vector_type(4)));

static __device__ __forceinline__ uint32_t pkh2(float a, float b) {
  __half2 h = __floats2half2_rn(a, b);
  return __builtin_bit_cast(uint32_t, h);
}
static __device__ __forceinline__ f32x4 mfma16(uint4 a, uint4 b, f32x4 c) {
  return __builtin_amdgcn_mfma_f32_16x16x32_f16(
      __builtin_bit_cast(f16x8, a), __builtin_bit_cast(f16x8, b), c, 0, 0, 0);
}

// ---------------- selector masks (depth-only, shared by both convs) ----------------
__global__ __launch_bounds__(256) void sel_kernel(
    const float* __restrict__ depth, const float* __restrict__ fxp,
    uint32_t* __restrict__ sel) {
  int idx = blockIdx.x*256 + threadIdx.x;           // 16*224*224 = 3136*256 exact
  int w = idx % HWD; int h = (idx / HWD) % HH; int n = idx / HWP;
  const float* dn = depth + n*HWP;
  float c = dn[h*HWD + w];
  float fx = fxp[0];
  float gr = c / fx;
  float half = gr * 0.5f;
  uint32_t bits = 0;
  #pragma unroll
  for (int i = 0; i < 3; ++i)
    #pragma unroll
    for (int j = 0; j < 3; ++j) {
      int y = h + i - 1, x = w + j - 1;
      float d = 0.0f;
      if (y >= 0 && y < HH && x >= 0 && x < HWD) d = dn[y*HWD + x];
      int k = i*3 + j;
      uint32_t b = 0;
      if (fabsf(d - (c + gr)) <= half) b |= 1u;   // m0 -> w0
      if (fabsf(d - c) < half)         b |= 2u;   // m1 -> w1 (strict <)
      if (fabsf(d - (c - gr)) <= half) b |= 4u;   // m2 -> w2
      bits |= b << (3*k);
    }
  sel[idx] = bits;
}

// ======== MFMA conv template (validated R4) ========
// A (M=16 px along x, K=32 = 2 taps x 16 c): lane l -> px r=l&15, tap parity l>>5,
//   c = ((l>>4)&1)*8 + e.  B: lane l -> o=l&15, same K map.  C/D: o=l&15, px=(l>>4)*4+reg.
// Mask m_j[px,tap] uniform over lane's 8 A elems -> AND-mask on A fragment.

// ---------------- conv1: 3->16 via MFMA (c padded 3->16 with zeros) ----------------
__global__ __launch_bounds__(256, 2) void conv1_kernel(
    const float* __restrict__ x, const uint32_t* __restrict__ sel,
    const float* __restrict__ w0, const float* __restrict__ w1,
    const float* __restrict__ w2, const float* __restrict__ bias,
    __half* __restrict__ h1t) {
  __shared__ __align__(16) char ubuf[15552];      // ts (15552B) / hbuf (2048B) union
  __shared__ __align__(16) uint4 wlds[15*64];     // B-frags
  __half* ts = (__half*)ubuf;                     // [py][px][c pad 24]
  __half* hbuf = (__half*)ubuf;                   // epilogue bounce (after barrier)
  int tid = threadIdx.x;
  int b = blockIdx.x;
  int n = b / 196; int rem = b % 196;
  int br = rem / 14, bc = rem % 14;
  int y0 = br*16 - 1, x0 = bc*16 - 1;
  const float* xn = x + (size_t)n*3*HWP;
  // ---- prefetch tile pixels into regs (2 px/lane, 3 scalar loads each) ----
  float pf[2][3];
  #pragma unroll
  for (int it = 0; it < 2; ++it) {
    int p = min(tid + it*256, 323);
    int gy = min(max(y0 + p/18, 0), HH-1);
    int gx = min(max(x0 + p%18, 0), HWD-1);
    size_t off = (size_t)gy*HWD + gx;
    pf[it][0] = xn[off]; pf[it][1] = xn[HWP + off]; pf[it][2] = xn[2*HWP + off];
  }
  // ---- write tile (3 uint4 per px: c0..2 + zeros) ----
  #pragma unroll
  for (int it = 0; it < 2; ++it) {
    int p = tid + it*256;
    if (p < 324) {
      uint4 v0 = { pkh2(pf[it][0], pf[it][1]), pkh2(pf[it][2], 0.f), 0u, 0u };
      uint4 z  = { 0u, 0u, 0u, 0u };
      *(uint4*)(ts + p*24)      = v0;
      *(uint4*)(ts + p*24 + 8)  = z;
      *(uint4*)(ts + p*24 + 16) = z;
    }
  }
  // ---- stage B-frags (branchless clamped loads) ----
  #pragma unroll
  for (int it = 0; it < 4; ++it) {
    int t = tid + it*256;
    int tc = min(t, 959);
    int lane = tc & 63; int pj = tc >> 6;
    int p = pj / 3, j = pj % 3;
    int o = lane & 15; int tap = p*2 + (lane >> 5);
    int cbase = ((lane >> 4) & 1) * 8;
    const float* wj = (j == 0) ? w0 : (j == 1) ? w1 : w2;
    float f[8];
    #pragma unroll
    for (int e = 0; e < 8; ++e) {
      int c = cbase + e;
      float v = wj[o*27 + min(c,2)*9 + min(tap,8)];
      f[e] = (tap <= 8 && c < 3) ? v : 0.f;
    }
    if (t < 960) {
      uint4 wv = { pkh2(f[0],f[1]), pkh2(f[2],f[3]), pkh2(f[4],f[5]), pkh2(f[6],f[7]) };
      wlds[pj*64 + lane] = wv;
    }
  }
  int lane = tid & 63, wid = tid >> 6;
  int r = lane & 15;
  float bo = bias[r];
  uint32_t sv[4];
  #pragma unroll
  for (int ty = 0; ty < 4; ++ty)
    sv[ty] = sel[(size_t)n*HWP + (br*16 + wid*4 + ty)*HWD + bc*16 + r];
  int tapPar = lane >> 5;
  int c0 = ((lane >> 4) & 1) * 8;
  __syncthreads();
  f32x4 acc[4] = {{0,0,0,0},{0,0,0,0},{0,0,0,0},{0,0,0,0}};
  #pragma unroll
  for (int p = 0; p < 5; ++p) {
    int ta = 2*p, tb = (2*p+1 > 8) ? 8 : 2*p+1;     // tap9 dups tap8 (B=0 kills it)
    int dyL = tapPar ? tb/3 : ta/3;
    int dxL = tapPar ? tb%3 : ta%3;
    int shL = 3*(tapPar ? 2*p+1 : 2*p);             // tap9 shift=27 -> bits are 0
    uint4 a[4];
    #pragma unroll
    for (int ty = 0; ty < 4; ++ty) {
      int ly = wid*4 + ty;
      a[ty] = *(const uint4*)(ts + ((ly + dyL)*18 + (r + dxL))*24 + c0);
    }
    #pragma unroll
    for (int j = 0; j < 3; ++j) {
      uint4 bf = wlds[(p*3 + j)*64 + lane];
      #pragma unroll
      for (int ty = 0; ty < 4; ++ty) {
        uint32_t msk = 0u - ((sv[ty] >> (shL + j)) & 1u);
        uint4 am = { a[ty].x & msk, a[ty].y & msk, a[ty].z & msk, a[ty].w & msk };
        acc[ty] = mfma16(am, bf, acc[ty]);
      }
    }
  }
  __syncthreads();                                   // ts -> hbuf reuse barrier
  // relu + write channel-last f16 (bounce via LDS for coalesced stores)
  #pragma unroll
  for (int ty = 0; ty < 4; ++ty) {
    int gy = br*16 + wid*4 + ty;
    #pragma unroll
    for (int e = 0; e < 4; ++e) {
      float v = fmaxf(acc[ty][e] + bo, 0.f);
      hbuf[wid*256 + ((lane>>4)*4 + e)*16 + r] = __float2half(v);
    }
    uint2 hw = *(uint2*)&hbuf[wid*256 + lane*4];
    *(uint2*)(h1t + ((size_t)(n*HWP + gy*HWD) + bc*16)*16 + lane*4) = hw;
  }
}

// ---------------- conv2: 16->16 via MFMA + ReLU + 2x2 maxpool -> pooled f16 CF ----------------
__global__ __launch_bounds__(256, 2) void conv2_kernel(
    const __half* __restrict__ h1t, const uint32_t* __restrict__ sel,
    const float* __restrict__ w0, const float* __restrict__ w1,
    const float* __restrict__ w2, const float* __restrict__ bias,
    __half* __restrict__ pooled) {
  __shared__ __align__(16) char ubuf[15552];      // ts (15552B) / pl (4352B) union
  __shared__ __align__(16) uint4 wlds[15*64];
  __half* ts = (__half*)ubuf;                     // [py][px][c pad 24]
  float* pl = (float*)ubuf;                       // pooled bounce (after barrier)
  int tid = threadIdx.x;
  int b = blockIdx.x;
  int n = b / 196; int rem = b % 196;
  int br = rem / 14, bc = rem % 14;
  int y0 = br*16 - 1, x0 = bc*16 - 1;
  const __half* hn = h1t + (size_t)n*HWP*16;
  // ---- prefetch tile into regs: 648 uint4 words (2 per px), 3/lane ----
  uint4 st[3];
  #pragma unroll
  for (int it = 0; it < 3; ++it) {
    int w = min(tid + it*256, 647);
    int p = w >> 1, hh = w & 1;
    int gy = min(max(y0 + p/18, 0), HH-1);
    int gx = min(max(x0 + p%18, 0), HWD-1);
    st[it] = *(const uint4*)(hn + ((size_t)(gy*HWD + gx))*16 + hh*8);
  }
  #pragma unroll
  for (int it = 0; it < 3; ++it) {
    int w = tid + it*256;
    if (w < 648) {
      int p = w >> 1, hh = w & 1;
      *(uint4*)(ts + p*24 + hh*8) = st[it];
    }
  }
  // ---- stage B-frags (branchless clamped loads) ----
  #pragma unroll
  for (int it = 0; it < 4; ++it) {
    int t = tid + it*256;
    int tc = min(t, 959);
    int lane = tc & 63; int pj = tc >> 6;
    int p = pj / 3, j = pj % 3;
    int o = lane & 15; int tap = p*2 + (lane >> 5);
    int cbase = ((lane >> 4) & 1) * 8;
    const float* wj = (j == 0) ? w0 : (j == 1) ? w1 : w2;
    const float* wp = wj + o*144 + cbase*9 + tap;   // [o][c][k]; tap=9 stays in-bounds
    float f[8];
    #pragma unroll
    for (int e = 0; e < 8; ++e) {
      float v = wp[e*9];
      f[e] = (tap <= 8) ? v : 0.f;
    }
    if (t < 960) {
      uint4 wv = { pkh2(f[0],f[1]), pkh2(f[2],f[3]), pkh2(f[4],f[5]), pkh2(f[6],f[7]) };
      wlds[pj*64 + lane] = wv;
    }
  }
  int lane = tid & 63, wid = tid >> 6;
  int r = lane & 15;
  float bo = bias[r];
  uint32_t sv[4];
  #pragma unroll
  for (int ty = 0; ty < 4; ++ty)
    sv[ty] = sel[(size_t)n*HWP + (br*16 + wid*4 + ty)*HWD + bc*16 + r];
  int tapPar = lane >> 5;
  int c0 = ((lane >> 4) & 1) * 8;
  __syncthreads();
  f32x4 acc[4] = {{0,0,0,0},{0,0,0,0},{0,0,0,0},{0,0,0,0}};
  #pragma unroll
  for (int p = 0; p < 5; ++p) {
    int ta = 2*p, tb = (2*p+1 > 8) ? 8 : 2*p+1;
    int dyL = tapPar ? tb/3 : ta/3;
    int dxL = tapPar ? tb%3 : ta%3;
    int shL = 3*(tapPar ? 2*p+1 : 2*p);
    uint4 a[4];
    #pragma unroll
    for (int ty = 0; ty < 4; ++ty) {
      int ly = wid*4 + ty;
      a[ty] = *(const uint4*)(ts + ((ly + dyL)*18 + (r + dxL))*24 + c0);
    }
    #pragma unroll
    for (int j = 0; j < 3; ++j) {
      uint4 bf = wlds[(p*3 + j)*64 + lane];
      #pragma unroll
      for (int ty = 0; ty < 4; ++ty) {
        uint32_t msk = 0u - ((sv[ty] >> (shL + j)) & 1u);
        uint4 am = { a[ty].x & msk, a[ty].y & msk, a[ty].z & msk, a[ty].w & msk };
        acc[ty] = mfma16(am, bf, acc[ty]);
      }
    }
  }
  __syncthreads();                                   // ts -> pl reuse barrier
  // relu + 2x2 maxpool: x-pairs within lane regs, y-pairs across tiles
  #pragma unroll
  for (int yp = 0; yp < 2; ++yp) {
    f32x4 v0 = acc[yp*2], v1 = acc[yp*2+1];
    float m00 = fmaxf(fmaxf(v0[0]+bo, 0.f), fmaxf(v0[1]+bo, 0.f));
    float m01 = fmaxf(fmaxf(v0[2]+bo, 0.f), fmaxf(v0[3]+bo, 0.f));
    float m10 = fmaxf(fmaxf(v1[0]+bo, 0.f), fmaxf(v1[1]+bo, 0.f));
    float m11 = fmaxf(fmaxf(v1[2]+bo, 0.f), fmaxf(v1[3]+bo, 0.f));
    int prow = wid*2 + yp;
    int pc0 = (lane >> 4)*2;
    pl[(prow*8 + pc0)*17 + r]     = fmaxf(m00, m10);
    pl[(prow*8 + pc0 + 1)*17 + r] = fmaxf(m01, m11);
  }
  __syncthreads();
  for (int t = tid; t < 1024; t += 256) {         // repack channel-first f16
    int oo = t >> 6; int pix = t & 63;
    int pr = pix >> 3, pc = pix & 7;
    pooled[(size_t)(n*16 + oo)*PHW + (br*8 + pr)*PW + bc*8 + pc] =
        __float2half(pl[pix*17 + oo]);
  }
}

// ---------------- FC1 via MFMA: A=pooled f16 [16 x K], B=wgt f32->f16 ----------------
// block = otile*196 + kseg; K-slice 1024 = 8 chunks x 128; chunk-level register prefetch.
__global__ __launch_bounds__(256) void fc1_kernel(
    const __half* __restrict__ hin, const float* __restrict__ wgt,
    float* __restrict__ partial) {
  __shared__ __align__(16) uint4 alds[4*64];
  __shared__ __align__(16) uint4 wlds[4*64];
  __shared__ __align__(16) f32x4 cacc[256];
  int tid = threadIdx.x;
  int otile = blockIdx.x / 196;
  int kseg  = blockIdx.x % 196;
  int obase = otile * 16;
  int lane = tid & 63, wid = tid >> 6;
  int q8 = tid & 15, row = tid >> 4;              // staging coords (16 rows x 16 k-octs)
  int sslot = (q8>>2)*64 + (row | ((q8&3) << 4));
  const __half* hp0 = hin + (size_t)row*FCK + kseg*1024 + q8*8;
  const float* wp0  = wgt + (size_t)(obase + row)*FCK + kseg*1024 + q8*8;
  uint4 hv; float4 wva, wvb;
  hv  = *(const uint4*)hp0;
  wva = *(const float4*)wp0;
  wvb = *(const float4*)(wp0 + 4);
  f32x4 acc = {0,0,0,0};
  for (int ch = 0; ch < 8; ++ch) {
    alds[sslot] = hv;
    uint4 wc = { pkh2(wva.x,wva.y), pkh2(wva.z,wva.w), pkh2(wvb.x,wvb.y), pkh2(wvb.z,wvb.w) };
    wlds[sslot] = wc;
    if (ch < 7) {                                  // issue next chunk's loads pre-barrier
      hv  = *(const uint4*)(hp0 + (ch+1)*128);
      wva = *(const float4*)(wp0 + (ch+1)*128);
      wvb = *(const float4*)(wp0 + (ch+1)*128 + 4);
    }
    __syncthreads();
    acc = mfma16(alds[wid*64 + lane], wlds[wid*64 + lane], acc);
    __syncthreads();
  }
  cacc[wid*64 + lane] = acc;
  __syncthreads();
  {
    int l = tid & 63, e = tid >> 6;
    float s = cacc[l][e] + cacc[64 + l][e] + cacc[128 + l][e] + cacc[192 + l][e];
    int nn = (l >> 4)*4 + e;
    int oo = l & 15;
    partial[((size_t)kseg*16 + nn)*128 + obase + oo] = s;
  }
}

__global__ __launch_bounds__(256) void fc1_reduce_kernel(
    const float* __restrict__ partial, const float* __restrict__ bias,
    float* __restrict__ outp) {
  int idx = blockIdx.x*256 + threadIdx.x;   // 2048
  int o = idx & 127;
  float s = bias[o];
  for (int k = 0; k < KSEG; ++k) s += partial[(size_t)k*2048 + idx];
  outp[idx] = s;
}

// ---------------- FC2 + log_softmax ----------------
__global__ __launch_bounds__(128) void fc2_kernel(
    const float* __restrict__ fin, const float* __restrict__ w,
    const float* __restrict__ b, float* __restrict__ out) {
  __shared__ float row[128];
  __shared__ float v[10];
  __shared__ float lse;
  int n = blockIdx.x, t = threadIdx.x;
  row[t] = fin[n*128 + t];
  __syncthreads();
  if (t < 10) {
    float s = b[t];
    const float* wr = w + t*128;
    for (int i = 0; i < 128; ++i) s += row[i]*wr[i];
    v[t] = s;
  }
  __syncthreads();
  if (t == 0) {
    float m = v[0];
    for (int i = 1; i < 10; ++i) m = fmaxf(m, v[i]);
    float se = 0.f;
    for (int i = 0; i < 10; ++i) se += expf(v[i] - m);
    lse = m + logf(se);
  }
  __syncthreads();
  if (t < 10) out[n*10 + t] = v[t] - lse;
}

extern "C" void kernel_launch(void* const* d_in, const int* in_sizes, int n_in,
                              void* d_out, int out_size, void* d_ws, size_t ws_size,
                              hipStream_t stream) {
  const float* x     = (const float*)d_in[0];
  const float* depth = (const float*)d_in[1];
  const float* fx    = (const float*)d_in[2];
  const float* c1w0  = (const float*)d_in[3];
  const float* c1w1  = (const float*)d_in[4];
  const float* c1w2  = (const float*)d_in[5];
  const float* c1b   = (const float*)d_in[6];
  const float* c2w0  = (const float*)d_in[7];
  const float* c2w1  = (const float*)d_in[8];
  const float* c2w2  = (const float*)d_in[9];
  const float* c2b   = (const float*)d_in[10];
  const float* fc1w  = (const float*)d_in[11];
  const float* fc1b  = (const float*)d_in[12];
  const float* fc2w  = (const float*)d_in[13];
  const float* fc2b  = (const float*)d_in[14];
  float* out = (float*)d_out;

  char* ws = (char*)d_ws;
  uint32_t* sel  = (uint32_t*)ws;                      // 3,211,264 B
  __half* h1t    = (__half*)(ws + 3211264);            // 25,690,112 B
  __half* pooled = (__half*)(ws + 28901376);           //  6,422,528 B
  float* partial = (float*)(ws + 35323904);            //  1,605,632 B
  float* fc1o    = (float*)(ws + 36929536);            //      8,192 B

  sel_kernel<<<3136, 256, 0, stream>>>(depth, fx, sel);
  conv1_kernel<<<3136, 256, 0, stream>>>(x, sel, c1w0, c1w1, c1w2, c1b, h1t);
  conv2_kernel<<<3136, 256, 0, stream>>>(h1t, sel, c2w0, c2w1, c2w2, c2b, pooled);
  fc1_kernel<<<1568, 256, 0, stream>>>(pooled, fc1w, partial);
  fc1_reduce_kernel<<<8, 256, 0, stream>>>(partial, fc1b, fc1o);
  fc2_kernel<<<16, 128, 0, stream>>>(fc1o, fc2w, fc2b, out);
}

// Round 6
// 114.935 us; speedup vs baseline: 3.4989x; 1.0721x over previous
//
#include <hip/hip_runtime.h>
#include <hip/hip_fp16.h>
#include <stdint.h>

#define HH 224
#define HWD 224
#define HWP (HH*HWD)      // 50176
#define PH 112
#define PW 112
#define PHW (PH*PW)       // 12544
#define FCK 200704
#define KSEG 196

typedef _Float16 f16x8 __attribute__((ext_vector_type(8)));
typedef float f32x4 __attribute__((ext_vector_type(4)));

static __device__ __forceinline__ uint32_t pkh2(float a, float b) {
  __half2 h = __floats2half2_rn(a, b);
  return __builtin_bit_cast(uint32_t, h);
}
static __device__ __forceinline__ f32x4 mfma16(uint4 a, uint4 b, f32x4 c) {
  return __builtin_amdgcn_mfma_f32_16x16x32_f16(
      __builtin_bit_cast(f16x8, a), __builtin_bit_cast(f16x8, b), c, 0, 0, 0);
}

// ---------------- selector masks (depth-only, shared by both convs) ----------------
__global__ __launch_bounds__(256) void sel_kernel(
    const float* __restrict__ depth, const float* __restrict__ fxp,
    uint32_t* __restrict__ sel) {
  int idx = blockIdx.x*256 + threadIdx.x;           // 16*224*224 = 3136*256 exact
  int w = idx % HWD; int h = (idx / HWD) % HH; int n = idx / HWP;
  const float* dn = depth + n*HWP;
  float c = dn[h*HWD + w];
  float fx = fxp[0];
  float gr = c / fx;
  float half = gr * 0.5f;
  uint32_t bits = 0;
  #pragma unroll
  for (int i = 0; i < 3; ++i)
    #pragma unroll
    for (int j = 0; j < 3; ++j) {
      int y = h + i - 1, x = w + j - 1;
      float d = 0.0f;
      if (y >= 0 && y < HH && x >= 0 && x < HWD) d = dn[y*HWD + x];
      int k = i*3 + j;
      uint32_t b = 0;
      if (fabsf(d - (c + gr)) <= half) b |= 1u;   // m0 -> w0
      if (fabsf(d - c) < half)         b |= 2u;   // m1 -> w1 (strict <)
      if (fabsf(d - (c - gr)) <= half) b |= 4u;   // m2 -> w2
      bits |= b << (3*k);
    }
  sel[idx] = bits;
}

// ======== MFMA conv template (validated R4) ========
// A (M=16 px along x, K=32 = 2 taps x 16 c): lane l -> px r=l&15, tap parity l>>5,
//   c = ((l>>4)&1)*8 + e.  B: lane l -> o=l&15, same K map.  C/D: o=l&15, px=(l>>4)*4+reg.
// Mask m_j[px,tap] uniform over lane's 8 A elems -> AND-mask on A fragment.
// R6: 4 tiles per block, software-pipelined (next tile's global loads issued
// before current tile's MFMA phase); B-frags staged once per block.

// ---------------- conv1: 3->16 via MFMA (c padded 3->16 with zeros) ----------------
__global__ __launch_bounds__(256, 4) void conv1_kernel(
    const float* __restrict__ x, const uint32_t* __restrict__ sel,
    const float* __restrict__ w0, const float* __restrict__ w1,
    const float* __restrict__ w2, const float* __restrict__ bias,
    __half* __restrict__ h1t) {
  __shared__ __align__(16) __half ts[648*24/2*2]; // 15552 B  [py][px][c pad 24] (324 px)
  __shared__ __align__(16) uint4 wlds[15*64];     // 15360 B
  __shared__ __align__(16) __half hbuf[1024];     //  2048 B epilogue bounce
  int tid = threadIdx.x;
  int lane = tid & 63, wid = tid >> 6;
  int r = lane & 15;
  int tapPar = lane >> 5;
  int c0 = ((lane >> 4) & 1) * 8;
  float bo = bias[r];

  // ---- stage B-frags once (branchless clamped loads) ----
  #pragma unroll
  for (int it = 0; it < 4; ++it) {
    int t = tid + it*256;
    int tc = min(t, 959);
    int ln = tc & 63; int pj = tc >> 6;
    int p = pj / 3, j = pj % 3;
    int o = ln & 15; int tap = p*2 + (ln >> 5);
    int cbase = ((ln >> 4) & 1) * 8;
    const float* wj = (j == 0) ? w0 : (j == 1) ? w1 : w2;
    float f[8];
    #pragma unroll
    for (int e = 0; e < 8; ++e) {
      int c = cbase + e;
      float v = wj[o*27 + min(c,2)*9 + min(tap,8)];
      f[e] = (tap <= 8 && c < 3) ? v : 0.f;
    }
    if (t < 960) {
      uint4 wv = { pkh2(f[0],f[1]), pkh2(f[2],f[3]), pkh2(f[4],f[5]), pkh2(f[6],f[7]) };
      wlds[pj*64 + ln] = wv;
    }
  }

  // ---- prefetch tile 0 into regs ----
  int tbase = blockIdx.x * 4;
  float pf[2][3]; uint32_t sv[4];
  {
    int tile = tbase;
    int n = tile/196, rem = tile%196, br = rem/14, bc = rem%14;
    int y0 = br*16 - 1, x0 = bc*16 - 1;
    const float* xn = x + (size_t)n*3*HWP;
    #pragma unroll
    for (int it = 0; it < 2; ++it) {
      int p = min(tid + it*256, 323);
      int gy = min(max(y0 + p/18, 0), HH-1);
      int gx = min(max(x0 + p%18, 0), HWD-1);
      size_t off = (size_t)gy*HWD + gx;
      pf[it][0] = xn[off]; pf[it][1] = xn[HWP + off]; pf[it][2] = xn[2*HWP + off];
    }
    #pragma unroll
    for (int ty = 0; ty < 4; ++ty)
      sv[ty] = sel[(size_t)n*HWP + (br*16 + wid*4 + ty)*HWD + bc*16 + r];
  }

  for (int ti = 0; ti < 4; ++ti) {
    int tile = tbase + ti;
    int n = tile/196, rem = tile%196, br = rem/14, bc = rem%14;
    // ---- ds_write current tile ----
    #pragma unroll
    for (int it = 0; it < 2; ++it) {
      int p = tid + it*256;
      if (p < 324) {
        uint4 v0 = { pkh2(pf[it][0], pf[it][1]), pkh2(pf[it][2], 0.f), 0u, 0u };
        uint4 z  = { 0u, 0u, 0u, 0u };
        *(uint4*)(ts + p*24)      = v0;
        *(uint4*)(ts + p*24 + 8)  = z;
        *(uint4*)(ts + p*24 + 16) = z;
      }
    }
    uint32_t svc[4];
    #pragma unroll
    for (int ty = 0; ty < 4; ++ty) svc[ty] = sv[ty];
    // ---- issue next tile's global loads (hidden under MFMA) ----
    if (ti < 3) {
      int tile2 = tile + 1;
      int n2 = tile2/196, rem2 = tile2%196, br2 = rem2/14, bc2 = rem2%14;
      int y0 = br2*16 - 1, x0 = bc2*16 - 1;
      const float* xn = x + (size_t)n2*3*HWP;
      #pragma unroll
      for (int it = 0; it < 2; ++it) {
        int p = min(tid + it*256, 323);
        int gy = min(max(y0 + p/18, 0), HH-1);
        int gx = min(max(x0 + p%18, 0), HWD-1);
        size_t off = (size_t)gy*HWD + gx;
        pf[it][0] = xn[off]; pf[it][1] = xn[HWP + off]; pf[it][2] = xn[2*HWP + off];
      }
      #pragma unroll
      for (int ty = 0; ty < 4; ++ty)
        sv[ty] = sel[(size_t)n2*HWP + (br2*16 + wid*4 + ty)*HWD + bc2*16 + r];
    }
    __syncthreads();
    // ---- MFMA phase ----
    f32x4 acc[4] = {{0,0,0,0},{0,0,0,0},{0,0,0,0},{0,0,0,0}};
    #pragma unroll
    for (int p = 0; p < 5; ++p) {
      int ta = 2*p, tb = (2*p+1 > 8) ? 8 : 2*p+1;   // tap9 dups tap8 (B=0 kills it)
      int dyL = tapPar ? tb/3 : ta/3;
      int dxL = tapPar ? tb%3 : ta%3;
      int shL = 3*(tapPar ? 2*p+1 : 2*p);
      uint4 a[4];
      #pragma unroll
      for (int ty = 0; ty < 4; ++ty) {
        int ly = wid*4 + ty;
        a[ty] = *(const uint4*)(ts + ((ly + dyL)*18 + (r + dxL))*24 + c0);
      }
      #pragma unroll
      for (int j = 0; j < 3; ++j) {
        uint4 bf = wlds[(p*3 + j)*64 + lane];
        #pragma unroll
        for (int ty = 0; ty < 4; ++ty) {
          uint32_t msk = 0u - ((svc[ty] >> (shL + j)) & 1u);
          uint4 am = { a[ty].x & msk, a[ty].y & msk, a[ty].z & msk, a[ty].w & msk };
          acc[ty] = mfma16(am, bf, acc[ty]);
        }
      }
    }
    // ---- epilogue: relu + channel-last f16 store via hbuf bounce ----
    #pragma unroll
    for (int ty = 0; ty < 4; ++ty) {
      int gy = br*16 + wid*4 + ty;
      #pragma unroll
      for (int e = 0; e < 4; ++e) {
        float v = fmaxf(acc[ty][e] + bo, 0.f);
        hbuf[wid*256 + ((lane>>4)*4 + e)*16 + r] = __float2half(v);
      }
      uint2 hw = *(uint2*)&hbuf[wid*256 + lane*4];
      *(uint2*)(h1t + ((size_t)(n*HWP + gy*HWD) + bc*16)*16 + lane*4) = hw;
    }
    __syncthreads();   // all reads of ts/hbuf done before next tile's writes
  }
}

// ---------------- conv2: 16->16 via MFMA + ReLU + 2x2 maxpool -> pooled f16 CF ----------------
__global__ __launch_bounds__(256, 4) void conv2_kernel(
    const __half* __restrict__ h1t, const uint32_t* __restrict__ sel,
    const float* __restrict__ w0, const float* __restrict__ w1,
    const float* __restrict__ w2, const float* __restrict__ bias,
    __half* __restrict__ pooled) {
  __shared__ __align__(16) __half ts[648*24/2*2]; // 15552 B
  __shared__ __align__(16) uint4 wlds[15*64];     // 15360 B
  __shared__ float pl[64*17];                     //  4352 B
  int tid = threadIdx.x;
  int lane = tid & 63, wid = tid >> 6;
  int r = lane & 15;
  int tapPar = lane >> 5;
  int c0 = ((lane >> 4) & 1) * 8;
  float bo = bias[r];

  // ---- stage B-frags once ----
  #pragma unroll
  for (int it = 0; it < 4; ++it) {
    int t = tid + it*256;
    int tc = min(t, 959);
    int ln = tc & 63; int pj = tc >> 6;
    int p = pj / 3, j = pj % 3;
    int o = ln & 15; int tap = p*2 + (ln >> 5);
    int cbase = ((ln >> 4) & 1) * 8;
    const float* wj = (j == 0) ? w0 : (j == 1) ? w1 : w2;
    const float* wp = wj + o*144 + cbase*9 + tap;   // [o][c][k]; tap=9 stays in-bounds
    float f[8];
    #pragma unroll
    for (int e = 0; e < 8; ++e) {
      float v = wp[e*9];
      f[e] = (tap <= 8) ? v : 0.f;
    }
    if (t < 960) {
      uint4 wv = { pkh2(f[0],f[1]), pkh2(f[2],f[3]), pkh2(f[4],f[5]), pkh2(f[6],f[7]) };
      wlds[pj*64 + ln] = wv;
    }
  }

  // ---- prefetch tile 0 ----
  int tbase = blockIdx.x * 4;
  uint4 st[3]; uint32_t sv[4];
  {
    int tile = tbase;
    int n = tile/196, rem = tile%196, br = rem/14, bc = rem%14;
    int y0 = br*16 - 1, x0 = bc*16 - 1;
    const __half* hn = h1t + (size_t)n*HWP*16;
    #pragma unroll
    for (int it = 0; it < 3; ++it) {
      int w = min(tid + it*256, 647);
      int p = w >> 1, hh = w & 1;
      int gy = min(max(y0 + p/18, 0), HH-1);
      int gx = min(max(x0 + p%18, 0), HWD-1);
      st[it] = *(const uint4*)(hn + ((size_t)(gy*HWD + gx))*16 + hh*8);
    }
    #pragma unroll
    for (int ty = 0; ty < 4; ++ty)
      sv[ty] = sel[(size_t)n*HWP + (br*16 + wid*4 + ty)*HWD + bc*16 + r];
  }

  for (int ti = 0; ti < 4; ++ti) {
    int tile = tbase + ti;
    int n = tile/196, rem = tile%196, br = rem/14, bc = rem%14;
    // ---- ds_write current tile ----
    #pragma unroll
    for (int it = 0; it < 3; ++it) {
      int w = tid + it*256;
      if (w < 648) {
        int p = w >> 1, hh = w & 1;
        *(uint4*)(ts + p*24 + hh*8) = st[it];
      }
    }
    uint32_t svc[4];
    #pragma unroll
    for (int ty = 0; ty < 4; ++ty) svc[ty] = sv[ty];
    // ---- issue next tile's loads ----
    if (ti < 3) {
      int tile2 = tile + 1;
      int n2 = tile2/196, rem2 = tile2%196, br2 = rem2/14, bc2 = rem2%14;
      int y0 = br2*16 - 1, x0 = bc2*16 - 1;
      const __half* hn = h1t + (size_t)n2*HWP*16;
      #pragma unroll
      for (int it = 0; it < 3; ++it) {
        int w = min(tid + it*256, 647);
        int p = w >> 1, hh = w & 1;
        int gy = min(max(y0 + p/18, 0), HH-1);
        int gx = min(max(x0 + p%18, 0), HWD-1);
        st[it] = *(const uint4*)(hn + ((size_t)(gy*HWD + gx))*16 + hh*8);
      }
      #pragma unroll
      for (int ty = 0; ty < 4; ++ty)
        sv[ty] = sel[(size_t)n2*HWP + (br2*16 + wid*4 + ty)*HWD + bc2*16 + r];
    }
    __syncthreads();
    // ---- MFMA phase ----
    f32x4 acc[4] = {{0,0,0,0},{0,0,0,0},{0,0,0,0},{0,0,0,0}};
    #pragma unroll
    for (int p = 0; p < 5; ++p) {
      int ta = 2*p, tb = (2*p+1 > 8) ? 8 : 2*p+1;
      int dyL = tapPar ? tb/3 : ta/3;
      int dxL = tapPar ? tb%3 : ta%3;
      int shL = 3*(tapPar ? 2*p+1 : 2*p);
      uint4 a[4];
      #pragma unroll
      for (int ty = 0; ty < 4; ++ty) {
        int ly = wid*4 + ty;
        a[ty] = *(const uint4*)(ts + ((ly + dyL)*18 + (r + dxL))*24 + c0);
      }
      #pragma unroll
      for (int j = 0; j < 3; ++j) {
        uint4 bf = wlds[(p*3 + j)*64 + lane];
        #pragma unroll
        for (int ty = 0; ty < 4; ++ty) {
          uint32_t msk = 0u - ((svc[ty] >> (shL + j)) & 1u);
          uint4 am = { a[ty].x & msk, a[ty].y & msk, a[ty].z & msk, a[ty].w & msk };
          acc[ty] = mfma16(am, bf, acc[ty]);
        }
      }
    }
    // ---- relu + 2x2 maxpool -> pl ----
    #pragma unroll
    for (int yp = 0; yp < 2; ++yp) {
      f32x4 v0 = acc[yp*2], v1 = acc[yp*2+1];
      float m00 = fmaxf(fmaxf(v0[0]+bo, 0.f), fmaxf(v0[1]+bo, 0.f));
      float m01 = fmaxf(fmaxf(v0[2]+bo, 0.f), fmaxf(v0[3]+bo, 0.f));
      float m10 = fmaxf(fmaxf(v1[0]+bo, 0.f), fmaxf(v1[1]+bo, 0.f));
      float m11 = fmaxf(fmaxf(v1[2]+bo, 0.f), fmaxf(v1[3]+bo, 0.f));
      int prow = wid*2 + yp;
      int pc0 = (lane >> 4)*2;
      pl[(prow*8 + pc0)*17 + r]     = fmaxf(m00, m10);
      pl[(prow*8 + pc0 + 1)*17 + r] = fmaxf(m01, m11);
    }
    __syncthreads();   // pl ready; also all ts reads done
    for (int t = tid; t < 1024; t += 256) {       // repack channel-first f16
      int oo = t >> 6; int pix = t & 63;
      int pr = pix >> 3, pc = pix & 7;
      pooled[(size_t)(n*16 + oo)*PHW + (br*8 + pr)*PW + bc*8 + pc] =
          __float2half(pl[pix*17 + oo]);
    }
    __syncthreads();   // pl reads done before next tile's pl writes (post-MFMA)
  }
}

// ---------------- FC1 via MFMA: A=pooled f16 [16 x K], B=wgt f32->f16 ----------------
// block = otile*196 + kseg; K-slice 1024 = 8 chunks x 128; LDS double-buffer,
// one barrier per chunk, chunk-level register prefetch.
__global__ __launch_bounds__(256) void fc1_kernel(
    const __half* __restrict__ hin, const float* __restrict__ wgt,
    float* __restrict__ partial) {
  __shared__ __align__(16) uint4 alds[2][256];
  __shared__ __align__(16) uint4 wlds[2][256];
  __shared__ __align__(16) f32x4 cacc[256];
  int tid = threadIdx.x;
  int otile = blockIdx.x / 196;
  int kseg  = blockIdx.x % 196;
  int obase = otile * 16;
  int lane = tid & 63, wid = tid >> 6;
  int q8 = tid & 15, row = tid >> 4;              // staging coords (16 rows x 16 k-octs)
  int sslot = (q8>>2)*64 + (row | ((q8&3) << 4));
  const __half* hp0 = hin + (size_t)row*FCK + kseg*1024 + q8*8;
  const float* wp0  = wgt + (size_t)(obase + row)*FCK + kseg*1024 + q8*8;
  uint4 hv; float4 wva, wvb;
  hv  = *(const uint4*)hp0;
  wva = *(const float4*)wp0;
  wvb = *(const float4*)(wp0 + 4);
  f32x4 acc = {0,0,0,0};
  for (int ch = 0; ch < 8; ++ch) {
    int buf = ch & 1;
    alds[buf][sslot] = hv;
    uint4 wc = { pkh2(wva.x,wva.y), pkh2(wva.z,wva.w), pkh2(wvb.x,wvb.y), pkh2(wvb.z,wvb.w) };
    wlds[buf][sslot] = wc;
    if (ch < 7) {                                  // issue next chunk's loads pre-barrier
      hv  = *(const uint4*)(hp0 + (ch+1)*128);
      wva = *(const float4*)(wp0 + (ch+1)*128);
      wvb = *(const float4*)(wp0 + (ch+1)*128 + 4);
    }
    __syncthreads();
    acc = mfma16(alds[buf][wid*64 + lane], wlds[buf][wid*64 + lane], acc);
  }
  cacc[wid*64 + lane] = acc;
  __syncthreads();
  {
    int l = tid & 63, e = tid >> 6;
    float s = cacc[l][e] + cacc[64 + l][e] + cacc[128 + l][e] + cacc[192 + l][e];
    int nn = (l >> 4)*4 + e;
    int oo = l & 15;
    partial[((size_t)kseg*16 + nn)*128 + obase + oo] = s;
  }
}

__global__ __launch_bounds__(256) void fc1_reduce_kernel(
    const float* __restrict__ partial, const float* __restrict__ bias,
    float* __restrict__ outp) {
  int idx = blockIdx.x*256 + threadIdx.x;   // 2048
  int o = idx & 127;
  float s = bias[o];
  for (int k = 0; k < KSEG; ++k) s += partial[(size_t)k*2048 + idx];
  outp[idx] = s;
}

// ---------------- FC2 + log_softmax ----------------
__global__ __launch_bounds__(128) void fc2_kernel(
    const float* __restrict__ fin, const float* __restrict__ w,
    const float* __restrict__ b, float* __restrict__ out) {
  __shared__ float row[128];
  __shared__ float v[10];
  __shared__ float lse;
  int n = blockIdx.x, t = threadIdx.x;
  row[t] = fin[n*128 + t];
  __syncthreads();
  if (t < 10) {
    float s = b[t];
    const float* wr = w + t*128;
    for (int i = 0; i < 128; ++i) s += row[i]*wr[i];
    v[t] = s;
  }
  __syncthreads();
  if (t == 0) {
    float m = v[0];
    for (int i = 1; i < 10; ++i) m = fmaxf(m, v[i]);
    float se = 0.f;
    for (int i = 0; i < 10; ++i) se += expf(v[i] - m);
    lse = m + logf(se);
  }
  __syncthreads();
  if (t < 10) out[n*10 + t] = v[t] - lse;
}

extern "C" void kernel_launch(void* const* d_in, const int* in_sizes, int n_in,
                              void* d_out, int out_size, void* d_ws, size_t ws_size,
                              hipStream_t stream) {
  const float* x     = (const float*)d_in[0];
  const float* depth = (const float*)d_in[1];
  const float* fx    = (const float*)d_in[2];
  const float* c1w0  = (const float*)d_in[3];
  const float* c1w1  = (const float*)d_in[4];
  const float* c1w2  = (const float*)d_in[5];
  const float* c1b   = (const float*)d_in[6];
  const float* c2w0  = (const float*)d_in[7];
  const float* c2w1  = (const float*)d_in[8];
  const float* c2w2  = (const float*)d_in[9];
  const float* c2b   = (const float*)d_in[10];
  const float* fc1w  = (const float*)d_in[11];
  const float* fc1b  = (const float*)d_in[12];
  const float* fc2w  = (const float*)d_in[13];
  const float* fc2b  = (const float*)d_in[14];
  float* out = (float*)d_out;

  char* ws = (char*)d_ws;
  uint32_t* sel  = (uint32_t*)ws;                      // 3,211,264 B
  __half* h1t    = (__half*)(ws + 3211264);            // 25,690,112 B
  __half* pooled = (__half*)(ws + 28901376);           //  6,422,528 B
  float* partial = (float*)(ws + 35323904);            //  1,605,632 B
  float* fc1o    = (float*)(ws + 36929536);            //      8,192 B

  sel_kernel<<<3136, 256, 0, stream>>>(depth, fx, sel);
  conv1_kernel<<<784, 256, 0, stream>>>(x, sel, c1w0, c1w1, c1w2, c1b, h1t);
  conv2_kernel<<<784, 256, 0, stream>>>(h1t, sel, c2w0, c2w1, c2w2, c2b, pooled);
  fc1_kernel<<<1568, 256, 0, stream>>>(pooled, fc1w, partial);
  fc1_reduce_kernel<<<8, 256, 0, stream>>>(partial, fc1b, fc1o);
  fc2_kernel<<<16, 128, 0, stream>>>(fc1o, fc2w, fc2b, out);
}